// Round 2
// baseline (364.769 us; speedup 1.0000x reference)
//
#include <hip/hip_runtime.h>
#include <stdint.h>

// Problem constants: B=4, N=32768, K=16, nqueries=2048, stride=16.
#define NPTS  32768
#define NQ    2048
#define KNN   16
#define NB    4
#define TS    1024            // points per LDS tile (float4-padded: 16 KB)
#define BLOCK 512
#define WPB   8               // waves (= queries) per block

// Exact wave-distributed top-16. Lanes 0..15 hold the sorted list (ascending
// by (dist, idx)); lane 15 is the exact threshold tau. Gate is d <= tau
// (superset, tie-index resolved exactly inside the insert via pos==16 no-op).
__device__ __forceinline__ void insert_all(float d, int p, int lane,
                                           float& ld, int& li, float& tau_d)
{
    unsigned long long rem = __ballot(d <= tau_d);
    while (rem) {
        const int srcl = __ffsll((unsigned long long)rem) - 1;
        const float wd = __shfl(d, srcl);
        const int   wi = __shfl(p, srcl);
        // position = #list elements strictly less than (wd, wi)
        const bool less = (ld < wd) || (ld == wd && li < wi);
        const unsigned long long lm = __ballot(less);
        const int pos = __popcll(lm & 0xffffull);
        const float pld = __shfl_up(ld, 1);
        const int   pli = __shfl_up(li, 1);
        if (lane < KNN) {
            if (lane == pos)      { ld = wd;  li = wi;  }
            else if (lane > pos)  { ld = pld; li = pli; }
            // pos == 16: candidate worse than whole list -> no-op
        }
        tau_d = __shfl(ld, 15);
        rem &= rem - 1;
        if (rem) rem &= __ballot(d <= tau_d);  // re-gate survivors (kills fill-phase storm)
    }
}

__global__ __launch_bounds__(BLOCK) void knn_kernel(const float* __restrict__ xyz,
                                                    float* __restrict__ out_idx,
                                                    float* __restrict__ out_pts)
{
    __shared__ float4 pts[TS];

    const int tid  = threadIdx.x;
    const int lane = tid & 63;
    const int wv   = tid >> 6;
    const int g    = blockIdx.x * WPB + wv;      // global query id
    const int b    = g >> 11;                    // g / NQ  (NQ = 2048)
    const int q    = g & (NQ - 1);
    const size_t base = (size_t)b * NPTS * 3;

    const int qp = q << 4;                       // stride-16 subsample
    const float qx = xyz[base + 3 * qp + 0];
    const float qy = xyz[base + 3 * qp + 1];
    const float qz = xyz[base + 3 * qp + 2];
    if (lane == 0) {
        out_pts[3 * g + 0] = qx;
        out_pts[3 * g + 1] = qy;
        out_pts[3 * g + 2] = qz;
    }

    float ld = __builtin_inff();  int li = 0x7fffffff;
    float tau_d = __builtin_inff();

    for (int tile = 0; tile < NPTS; tile += TS) {
        __syncthreads();   // previous tile fully consumed
        {   // stage 2 points per thread, xyz -> float4-padded AOS
            const float2* src = (const float2*)(xyz + base + (size_t)tile * 3);
            const float2 f0 = src[3 * tid + 0];
            const float2 f1 = src[3 * tid + 1];
            const float2 f2 = src[3 * tid + 2];
            pts[2 * tid + 0] = make_float4(f0.x, f0.y, f1.x, 0.f);
            pts[2 * tid + 1] = make_float4(f1.y, f2.x, f2.y, 0.f);
        }
        __syncthreads();

        const float4* lp = pts + 4 * lane;       // single vaddr; imm offsets below
        #pragma unroll
        for (int k = 0; k < TS / 256; ++k) {
            float dj[4];
            #pragma unroll
            for (int j = 0; j < 4; ++j) {
                const float4 p = lp[256 * k + j];        // ds_read_b128, imm offset
                // exact numpy order: ((dx*dx + dy*dy) + dz*dz), no FMA
                const float dx = __fadd_rn(p.x, -qx);
                const float dy = __fadd_rn(p.y, -qy);
                const float dz = __fadd_rn(p.z, -qz);
                dj[j] = __fadd_rn(__fadd_rn(__fmul_rn(dx, dx), __fmul_rn(dy, dy)),
                                  __fmul_rn(dz, dz));
            }
            const float dmin = fminf(fminf(dj[0], dj[1]), fminf(dj[2], dj[3]));
            if (__ballot(dmin <= tau_d)) {
                const int pbase = tile + 256 * k + 4 * lane;
                #pragma unroll
                for (int j = 0; j < 4; ++j)
                    insert_all(dj[j], pbase + j, lane, ld, li, tau_d);
            }
        }
    }

    // lanes 0..15 hold ranks 0..15 ascending -> coalesced store
    if (lane < KNN) {
        out_idx[(size_t)g * KNN + lane] = (float)li;
    }
}

extern "C" void kernel_launch(void* const* d_in, const int* in_sizes, int n_in,
                              void* d_out, int out_size, void* d_ws, size_t ws_size,
                              hipStream_t stream) {
    const float* xyz = (const float*)d_in[0];
    float* out = (float*)d_out;
    float* out_idx = out;                                 // NB*NQ*KNN floats
    float* out_pts = out + (size_t)NB * NQ * KNN;         // NB*NQ*3 floats

    const int blocks = (NB * NQ) / WPB;                   // 1024
    knn_kernel<<<blocks, BLOCK, 0, stream>>>(xyz, out_idx, out_pts);
}

// Round 3
// 215.773 us; speedup vs baseline: 1.6905x; 1.6905x over previous
//
#include <hip/hip_runtime.h>
#include <stdint.h>

// Problem constants: B=4, N=32768, K=16, nqueries=2048, stride=16.
#define NPTS  32768
#define NQ    2048
#define KNN   16
#define NB    4
#define TS    2048            // points per LDS tile (float4-padded: 32 KB)
#define BLOCK 512
#define WPB   8               // waves per block (2 queries per wave -> 16 q/block)

// Exact distributed top-16. Query t (t=0,1) of this wave keeps its sorted list
// (ascending by (dist,idx)) in lanes 16t..16t+15; lane 16t+15 holds the exact
// threshold tau_t. Gate d <= tau is a superset; ties resolved exactly in the
// insert (pos==16 -> no-op). Candidates serialized via ballot/ffs; position by
// group-masked ballot popcount; shift via shfl_up(1) (never crosses into a
// used lane of another group: gl==0 never shifts).
__device__ __forceinline__ void insert_all(float d, int p, int lane, int t,
                                           float& ld, int& li, float& tau)
{
    unsigned long long rem = __ballot(d <= tau);
    while (rem) {
        const int srcl = __ffsll((unsigned long long)rem) - 1;
        const float wd = __shfl(d, srcl);
        const int   wi = __shfl(p, srcl);
        const bool less = (ld < wd) || (ld == wd && li < wi);
        const unsigned long long lm = __ballot(less);
        const int pos = __popc((unsigned)((lm >> (16 * t)) & 0xffffull));
        const float pld = __shfl_up(ld, 1);
        const int   pli = __shfl_up(li, 1);
        if ((lane >> 4) == t) {
            const int gl = lane & 15;
            if (gl == pos)      { ld = wd;  li = wi;  }
            else if (gl > pos)  { ld = pld; li = pli; }
            // pos == 16: candidate worse than whole list -> no-op
        }
        tau = __shfl(ld, 16 * t + 15);
        rem &= rem - 1;
        if (rem) rem &= __ballot(d <= tau);   // re-gate survivors (fill-phase)
    }
}

__global__ __launch_bounds__(BLOCK) void knn_kernel(const float* __restrict__ xyz,
                                                    float* __restrict__ out_idx,
                                                    float* __restrict__ out_pts)
{
    __shared__ float4 pts[TS];

    const int tid  = threadIdx.x;
    const int lane = tid & 63;
    const int wv   = tid >> 6;
    const int w    = blockIdx.x * WPB + wv;   // wave id in [0, 4096)
    const int b    = w >> 10;                 // 1024 waves per batch
    const int pr   = w & 1023;                // query pair index
    const size_t base = (size_t)b * NPTS * 3;

    const int qp0 = pr << 5;                  // point idx of query 2*pr
    const int qp1 = qp0 + 16;                 // point idx of query 2*pr+1
    const float qx0 = xyz[base + 3 * qp0 + 0];
    const float qy0 = xyz[base + 3 * qp0 + 1];
    const float qz0 = xyz[base + 3 * qp0 + 2];
    const float qx1 = xyz[base + 3 * qp1 + 0];
    const float qy1 = xyz[base + 3 * qp1 + 1];
    const float qz1 = xyz[base + 3 * qp1 + 2];

    const int g0 = b * NQ + (pr << 1);        // global query id of q0 (q1=g0+1)
    if (lane == 0) {
        out_pts[3 * g0 + 0] = qx0;
        out_pts[3 * g0 + 1] = qy0;
        out_pts[3 * g0 + 2] = qz0;
        out_pts[3 * g0 + 3] = qx1;
        out_pts[3 * g0 + 4] = qy1;
        out_pts[3 * g0 + 5] = qz1;
    }

    float ld = __builtin_inff();  int li = 0x7fffffff;
    float tau0 = __builtin_inff(), tau1 = __builtin_inff();

    for (int tile = 0; tile < NPTS; tile += TS) {
        __syncthreads();   // previous tile fully consumed
        {   // stage TS points, xyz packed float3 -> float4-padded AOS
            const float2* src = (const float2*)(xyz + base + (size_t)tile * 3);
            #pragma unroll
            for (int t = 0; t < TS / (2 * BLOCK); ++t) {
                const int pi = tid + t * BLOCK;          // pair-of-points index
                const float2 f0 = src[3 * pi + 0];
                const float2 f1 = src[3 * pi + 1];
                const float2 f2 = src[3 * pi + 2];
                pts[2 * pi + 0] = make_float4(f0.x, f0.y, f1.x, 0.f);
                pts[2 * pi + 1] = make_float4(f1.y, f2.x, f2.y, 0.f);
            }
        }
        __syncthreads();

        #pragma unroll
        for (int k = 0; k < TS / 256; ++k) {
            float d0[4], d1[4];
            bool any = false;
            #pragma unroll
            for (int j = 0; j < 4; ++j) {
                // consecutive-lane float4: conflict-free, single vaddr + imm offs
                const float4 p = pts[256 * k + 64 * j + lane];
                // exact numpy order: ((dx*dx + dy*dy) + dz*dz), no FMA
                const float ax = __fadd_rn(p.x, -qx0);
                const float ay = __fadd_rn(p.y, -qy0);
                const float az = __fadd_rn(p.z, -qz0);
                d0[j] = __fadd_rn(__fadd_rn(__fmul_rn(ax, ax), __fmul_rn(ay, ay)),
                                  __fmul_rn(az, az));
                const float bx = __fadd_rn(p.x, -qx1);
                const float by = __fadd_rn(p.y, -qy1);
                const float bz = __fadd_rn(p.z, -qz1);
                d1[j] = __fadd_rn(__fadd_rn(__fmul_rn(bx, bx), __fmul_rn(by, by)),
                                  __fmul_rn(bz, bz));
                any = any | (d0[j] <= tau0) | (d1[j] <= tau1);
            }
            if (__ballot(any)) {
                const int pb = tile + 256 * k + lane;
                #pragma unroll
                for (int j = 0; j < 4; ++j) {
                    insert_all(d0[j], pb + 64 * j, lane, 0, ld, li, tau0);
                    insert_all(d1[j], pb + 64 * j, lane, 1, ld, li, tau1);
                }
            }
        }
    }

    // lanes 0..15: q0 ranks 0..15; lanes 16..31: q1 ranks 0..15 (g1 = g0+1)
    if (lane < 2 * KNN) {
        out_idx[(size_t)g0 * KNN + lane] = (float)li;
    }
}

extern "C" void kernel_launch(void* const* d_in, const int* in_sizes, int n_in,
                              void* d_out, int out_size, void* d_ws, size_t ws_size,
                              hipStream_t stream) {
    const float* xyz = (const float*)d_in[0];
    float* out = (float*)d_out;
    float* out_idx = out;                                 // NB*NQ*KNN floats
    float* out_pts = out + (size_t)NB * NQ * KNN;         // NB*NQ*3 floats

    const int blocks = (NB * NQ / 2) / WPB;               // 512
    knn_kernel<<<blocks, BLOCK, 0, stream>>>(xyz, out_idx, out_pts);
}